// Round 8
// baseline (1563.083 us; speedup 1.0000x reference)
//
#include <hip/hip_runtime.h>
#include <hip/hip_bf16.h>
#include <hip/hip_cooperative_groups.h>

namespace cg = cooperative_groups;

#define TT 256
#define BB 64
#define HH 512
#define EE 256
#define G4 2048
#define LL 9

typedef short bf16x8 __attribute__((ext_vector_type(8)));
typedef float f32x4 __attribute__((ext_vector_type(4)));
typedef unsigned long long u64;

static __device__ __forceinline__ unsigned short f2bf(float f) {
    unsigned u = __builtin_bit_cast(unsigned, f);
    u += 0x7FFFu + ((u >> 16) & 1u);   // RNE
    return (unsigned short)(u >> 16);
}
static __device__ __forceinline__ float bf2f(unsigned short s) {
    unsigned u = ((unsigned)s) << 16;
    return __builtin_bit_cast(float, u);
}
static __device__ __forceinline__ float sigf(float x) { return 1.f / (1.f + __expf(-x)); }
static __device__ __forceinline__ float tanhf_(float x) {
    float cx = fminf(fmaxf(x, -15.f), 15.f);
    float e = __expf(2.f * cx);
    return (e - 1.f) / (e + 1.f);
}

// ---------------------------------------------------------------------------
// Kernel 1: xW = (emb[ids] @ w_ih^T) + b_ih + b_hh, both directions, bf16 MFMA.
// Output TRANSPOSED: xw[dir][t][n][b] (bf16). (validated)
// ---------------------------------------------------------------------------
__global__ __launch_bounds__(256) void xw_gemm(
    const int* __restrict__ ids, const float* __restrict__ emb,
    const float* __restrict__ w_ih_f, const float* __restrict__ b_ih_f, const float* __restrict__ b_hh_f,
    const float* __restrict__ w_ih_b, const float* __restrict__ b_ih_b, const float* __restrict__ b_hh_b,
    unsigned short* __restrict__ xw)
{
    const int dir = blockIdx.z;
    const float* w_ih = dir ? w_ih_b : w_ih_f;
    const float* bi   = dir ? b_ih_b : b_ih_f;
    const float* bh   = dir ? b_hh_b : b_hh_f;
    const int n0 = blockIdx.y * 128;
    const int m0 = blockIdx.x * 128;
    const int tid = threadIdx.x;
    const int lane = tid & 63;
    const int wave = tid >> 6;
    const int wn = (wave & 1) * 64;
    const int wm = (wave >> 1) * 64;

    __shared__ short Wt[128][40];
    __shared__ short Xt[128][40];

    int rowid[4];
    #pragma unroll
    for (int i = 0; i < 4; ++i) {
        int p = tid + i * 256;
        int r = p >> 3;
        int m = m0 + r;
        int t = m >> 6, b = m & 63;
        int tx = dir ? (TT - 1 - t) : t;
        rowid[i] = ids[b * TT + tx];
    }

    f32x4 acc[4][4];
    #pragma unroll
    for (int a = 0; a < 4; ++a)
        #pragma unroll
        for (int c = 0; c < 4; ++c) acc[a][c] = (f32x4){0.f, 0.f, 0.f, 0.f};

    const int kb8 = (lane >> 4) * 8;
    const int l15 = lane & 15;

    for (int kt = 0; kt < 8; ++kt) {
        int k0 = kt * 32;
        #pragma unroll
        for (int i = 0; i < 4; ++i) {
            int p = tid + i * 256;
            int r = p >> 3;
            int kq = (p & 7) * 4;
            float4 wv = *(const float4*)(w_ih + (size_t)(n0 + r) * EE + k0 + kq);
            *(short4*)&Wt[r][kq] = make_short4((short)f2bf(wv.x), (short)f2bf(wv.y),
                                               (short)f2bf(wv.z), (short)f2bf(wv.w));
            float4 xv = *(const float4*)(emb + (size_t)rowid[i] * EE + k0 + kq);
            *(short4*)&Xt[r][kq] = make_short4((short)f2bf(xv.x), (short)f2bf(xv.y),
                                               (short)f2bf(xv.z), (short)f2bf(xv.w));
        }
        __syncthreads();
        bf16x8 af[4], bfv[4];
        #pragma unroll
        for (int nt = 0; nt < 4; ++nt) af[nt]  = *(const bf16x8*)&Wt[wn + nt * 16 + l15][kb8];
        #pragma unroll
        for (int mt = 0; mt < 4; ++mt) bfv[mt] = *(const bf16x8*)&Xt[wm + mt * 16 + l15][kb8];
        #pragma unroll
        for (int nt = 0; nt < 4; ++nt)
            #pragma unroll
            for (int mt = 0; mt < 4; ++mt)
                acc[nt][mt] = __builtin_amdgcn_mfma_f32_16x16x32_bf16(af[nt], bfv[mt], acc[nt][mt], 0, 0, 0);
        __syncthreads();
    }

    unsigned short* xwp = xw + (size_t)dir * TT * G4 * BB;
    #pragma unroll
    for (int nt = 0; nt < 4; ++nt) {
        #pragma unroll
        for (int r = 0; r < 4; ++r) {
            int n = n0 + wn + nt * 16 + (lane >> 4) * 4 + r;
            float bias = bi[n] + bh[n];
            #pragma unroll
            for (int mt = 0; mt < 4; ++mt) {
                int m = m0 + wm + mt * 16 + l15;
                int t = m >> 6, b = m & 63;
                xwp[((size_t)t * G4 + n) * BB + b] = f2bf(acc[nt][mt][r] + bias);
            }
        }
    }
}

// ---------------------------------------------------------------------------
// Kernel 2: LSTM recurrence, flag-synced islands (no grid.sync).
//  (a) lane-contiguous 8B staging loads (coalesced: 256 L3 line-requests per
//      WG-step instead of 2048),
//  (b) fragment-major swizzled LDS (frag read = bijective lane permutation),
//  (c) per-wave flags posted after per-wave vmcnt(0); ALL waves poll
//      independently -> exactly ONE s_barrier per step (stage-ready).
// WAR safety: flag(s+1) from wave V implies V's stage loads of buf[s&1] and
// V's LDS frag reads retired (program order + vmcnt(0) before flag post).
// Producers overwrite buf[s&1] only after observing all flags >= s+1.
// ---------------------------------------------------------------------------
__global__ __launch_bounds__(256, 1) void lstm_rec(
    const float* __restrict__ w_hh_f, const float* __restrict__ w_hh_b,
    const unsigned short* __restrict__ xw,   // [2][T][2048][64] bf16
    unsigned short* __restrict__ h_all,      // [2][T][64][512] bf16
    unsigned short* __restrict__ h_buf,      // [8 isl][2 buf][16][512] bf16
    unsigned int*   __restrict__ flags)      // [8 isl][64 waves]
{
    const int wg  = blockIdx.x;
    const int d   = wg >> 6;          // direction
    const int bg  = (wg >> 4) & 3;    // batch group (16 rows)
    const int ug  = wg & 15;          // unit group (32 units)
    const int isl = d * 4 + bg;

    const int tid  = threadIdx.x;
    const int lane = tid & 63;
    const int wv   = tid >> 6;
    const int bl   = lane & 15;       // local batch row
    const int jp   = lane >> 4;       // 0..3
    const int kb8  = jp * 8;
    const int uwb  = ug * 32 + wv * 8;    // wave's unit base (8 units)
    const int u_w  = uwb + jp * 2;        // this thread's 2 units
    const int b_abs = bg * 16 + bl;
    const int wid  = ug * 4 + wv;         // island wave id 0..63

    const float* w_hh = d ? w_hh_b : w_hh_f;

    // --- load w_hh fragments into registers (once) ---
    bf16x8 Bf[2][16];
    #pragma unroll
    for (int ct = 0; ct < 2; ++ct) {
        int c = ct * 16 + bl;                 // col within wave's 32
        int g = c >> 3, j = c & 7;
        int n = g * HH + uwb + j;
        #pragma unroll
        for (int ks = 0; ks < 16; ++ks) {
            int k = ks * 32 + kb8;
            float4 w0 = *(const float4*)(w_hh + (size_t)n * HH + k);
            float4 w1 = *(const float4*)(w_hh + (size_t)n * HH + k + 4);
            bf16x8 v;
            v[0] = (short)f2bf(w0.x); v[1] = (short)f2bf(w0.y);
            v[2] = (short)f2bf(w0.z); v[3] = (short)f2bf(w0.w);
            v[4] = (short)f2bf(w1.x); v[5] = (short)f2bf(w1.y);
            v[6] = (short)f2bf(w1.z); v[7] = (short)f2bf(w1.w);
            Bf[ct][ks] = v;
        }
    }

    __shared__ char h_lds[16 * 1024];         // fragment-major, XOR-swizzled
    __shared__ float gx[4][16 * 33 + 16];     // per-wave transpose region
    float* gw = &gx[wv][0];
    unsigned int* flg = flags + isl * 64;
    unsigned short* hbase = h_buf + (size_t)isl * 2 * 16 * HH;

    // staging constants: thread handles 8B granules gg = tid & 127 of rows
    // r = i*2 + (wv>>1); granule gg -> ks = gg>>3, jpw = (gg>>1)&3, half = gg&1
    const int ggS  = tid & 127;
    const int ksS  = ggS >> 3;
    const int jpwS = (ggS >> 1) & 3;
    const int hlfS = ggS & 1;
    const int rbS  = wv >> 1;

    float creg0 = 0.f, creg1 = 0.f;

    for (int s = 0; s < TT; ++s) {
        // ---- xw loads for this step: independent of h, issue before poll ----
        const unsigned short* xp = xw + ((size_t)(d * TT + s) * G4) * BB;
        unsigned short xr[4][2];
        #pragma unroll
        for (int g = 0; g < 4; ++g) {
            xr[g][0] = xp[(size_t)(g * HH + u_w + 0) * BB + b_abs];
            xr[g][1] = xp[(size_t)(g * HH + u_w + 1) * BB + b_abs];
        }

        // ---- every wave polls all 64 island wave-flags ----
        if (s) {
            int spin = 0;
            while (true) {
                unsigned int v = __hip_atomic_load(flg + lane, __ATOMIC_RELAXED,
                                                   __HIP_MEMORY_SCOPE_AGENT);
                if (__all((int)v >= s)) break;
                if (++spin > (1 << 14)) break;   // safety valve
            }
        }
        asm volatile("" ::: "memory");
        __builtin_amdgcn_sched_barrier(0);

        // ---- WG-cooperative coalesced staging: 8 x 8B lane-contiguous ----
        const u64* hb8 = (const u64*)(hbase + (size_t)(s & 1) * 16 * HH);
        u64 q[8];
        #pragma unroll
        for (int i = 0; i < 8; ++i)
            q[i] = __hip_atomic_load(hb8 + i * 256 + tid, __ATOMIC_RELAXED,
                                     __HIP_MEMORY_SCOPE_AGENT);
        #pragma unroll
        for (int i = 0; i < 8; ++i) {
            int r = i * 2 + rbS;
            int slot = (jpwS * 16 + r) ^ (ksS & 7);
            *(u64*)(h_lds + ksS * 1024 + slot * 16 + hlfS * 8) = q[i];
        }
        asm volatile("s_waitcnt lgkmcnt(0)" ::: "memory");
        __builtin_amdgcn_sched_barrier(0);
        __builtin_amdgcn_s_barrier();            // h_lds ready (only barrier)
        asm volatile("" ::: "memory");

        // ---- frag read (bijective lane->slot permutation) + 32 MFMA ----
        f32x4 acc0 = (f32x4){0.f, 0.f, 0.f, 0.f};
        f32x4 acc1 = (f32x4){0.f, 0.f, 0.f, 0.f};
        #pragma unroll
        for (int ks = 0; ks < 16; ++ks) {
            bf16x8 a = *(const bf16x8*)(h_lds + ks * 1024 + ((lane ^ (ks & 7)) << 4));
            acc0 = __builtin_amdgcn_mfma_f32_16x16x32_bf16(a, Bf[0][ks], acc0, 0, 0, 0);
            acc1 = __builtin_amdgcn_mfma_f32_16x16x32_bf16(a, Bf[1][ks], acc1, 0, 0, 0);
        }

        // ---- per-wave LDS transpose: D[row=batch=(jp*4+r)][col=gate=bl] ----
        #pragma unroll
        for (int r = 0; r < 4; ++r) {
            gw[(jp * 4 + r) * 33 + 0 * 16 + bl] = acc0[r];
            gw[(jp * 4 + r) * 33 + 1 * 16 + bl] = acc1[r];
        }
        asm volatile("s_waitcnt lgkmcnt(0)" ::: "memory");
        __builtin_amdgcn_sched_barrier(0);
        float gvv[4][2];
        #pragma unroll
        for (int g = 0; g < 4; ++g) {
            gvv[g][0] = gw[bl * 33 + g * 8 + jp * 2 + 0];
            gvv[g][1] = gw[bl * 33 + g * 8 + jp * 2 + 1];
        }

        // ---- gates (fp32) for this thread's 2 units ----
        unsigned int hu = 0;
        {
            float gi = gvv[0][0] + bf2f(xr[0][0]);
            float gf = gvv[1][0] + bf2f(xr[1][0]);
            float gg = gvv[2][0] + bf2f(xr[2][0]);
            float go = gvv[3][0] + bf2f(xr[3][0]);
            float cc = sigf(gf) * creg0 + sigf(gi) * tanhf_(gg);
            float hv = sigf(go) * tanhf_(cc);
            creg0 = cc;
            hu = (unsigned int)f2bf(hv);
        }
        {
            float gi = gvv[0][1] + bf2f(xr[0][1]);
            float gf = gvv[1][1] + bf2f(xr[1][1]);
            float gg = gvv[2][1] + bf2f(xr[2][1]);
            float go = gvv[3][1] + bf2f(xr[3][1]);
            float cc = sigf(gf) * creg1 + sigf(gi) * tanhf_(gg);
            float hv = sigf(go) * tanhf_(cc);
            creg1 = cc;
            hu |= ((unsigned int)f2bf(hv)) << 16;
        }

        // ---- publish h(s+1) slice + h_all; per-wave drain; per-wave flag ----
        unsigned short* hn = hbase + (size_t)((s + 1) & 1) * 16 * HH;
        __hip_atomic_store((unsigned int*)(hn + (size_t)bl * HH + u_w), hu,
                           __ATOMIC_RELAXED, __HIP_MEMORY_SCOPE_AGENT);
        int tout = d ? (TT - 1 - s) : s;
        *(unsigned int*)(h_all + ((size_t)(d * TT + tout) * BB + b_abs) * HH + u_w) = hu;

        asm volatile("s_waitcnt vmcnt(0)" ::: "memory");
        __builtin_amdgcn_sched_barrier(0);
        if (lane == 0)
            __hip_atomic_store(flg + wid, (unsigned int)(s + 1),
                               __ATOMIC_RELAXED, __HIP_MEMORY_SCOPE_AGENT);
    }
}

// ---------------------------------------------------------------------------
// Kernel 3: emissions (unchanged)
// ---------------------------------------------------------------------------
__global__ __launch_bounds__(256) void emis(
    const unsigned short* __restrict__ h_all,
    const float* __restrict__ w_out, const float* __restrict__ b_out,
    float* __restrict__ em)
{
    int p = blockIdx.x * 4 + (threadIdx.x >> 6);
    int lane = threadIdx.x & 63;
    int t = p >> 6, b = p & 63;
    bf16x8 vf = *(const bf16x8*)(h_all + ((size_t)(0 * TT + t) * BB + b) * HH + lane * 8);
    bf16x8 vb = *(const bf16x8*)(h_all + ((size_t)(1 * TT + t) * BB + b) * HH + lane * 8);
    float hf[8], hbk[8];
    #pragma unroll
    for (int i = 0; i < 8; ++i) { hf[i] = bf2f((unsigned short)vf[i]); hbk[i] = bf2f((unsigned short)vb[i]); }
    #pragma unroll
    for (int l = 0; l < LL; ++l) {
        const float* wr = w_out + (size_t)l * (2 * HH);
        float a = 0.f;
        float4 w0 = *(const float4*)(wr + lane * 8);
        float4 w1 = *(const float4*)(wr + lane * 8 + 4);
        float4 w2 = *(const float4*)(wr + HH + lane * 8);
        float4 w3 = *(const float4*)(wr + HH + lane * 8 + 4);
        a += hf[0]*w0.x + hf[1]*w0.y + hf[2]*w0.z + hf[3]*w0.w;
        a += hf[4]*w1.x + hf[5]*w1.y + hf[6]*w1.z + hf[7]*w1.w;
        a += hbk[0]*w2.x + hbk[1]*w2.y + hbk[2]*w2.z + hbk[3]*w2.w;
        a += hbk[4]*w3.x + hbk[5]*w3.y + hbk[6]*w3.z + hbk[7]*w3.w;
        #pragma unroll
        for (int o = 32; o; o >>= 1) a += __shfl_xor(a, o);
        if (lane == l) em[((size_t)t * BB + b) * LL + l] = a + b_out[l];
    }
}

// ---------------------------------------------------------------------------
// Kernel 4: CRF log-likelihood (unchanged)
// ---------------------------------------------------------------------------
__global__ __launch_bounds__(64) void crf(
    const float* __restrict__ em, const int* __restrict__ labels,
    const int* __restrict__ attn, const float* __restrict__ start,
    const float* __restrict__ endt, const float* __restrict__ trans,
    float* __restrict__ llh)
{
    int b = blockIdx.x;
    int j = threadIdx.x;
    bool act = j < LL;
    int jj = act ? j : 0;
    float tr[LL];
    #pragma unroll
    for (int i = 0; i < LL; ++i) tr[i] = act ? trans[i * LL + j] : 0.f;
    float st = act ? start[j] : 0.f;
    float en = act ? endt[j] : 0.f;

    int lab0 = labels[b * TT];
    int tg0 = (lab0 == -100) ? 0 : lab0;
    float em0 = em[((size_t)0 * BB + b) * LL + jj];
    float alpha = act ? (st + em0) : -3e38f;
    float score = __shfl(st + em0, tg0);
    int prev = tg0;

    for (int t = 1; t < TT; ++t) {
        int lab = labels[b * TT + t];
        int am  = attn[b * TT + t];
        int tg  = (lab == -100) ? 0 : lab;
        bool valid = (lab != -100) && (am > 0);
        float emj = em[((size_t)t * BB + b) * LL + jj];
        float trv = trans[prev * LL + jj];
        float s_tr = __shfl(trv, tg);
        float s_em = __shfl(emj, tg);
        if (valid) { score += s_tr + s_em; prev = tg; }
        float term[LL];
        float mx = -3e38f;
        #pragma unroll
        for (int i = 0; i < LL; ++i) {
            float ai = __shfl(alpha, i);
            term[i] = ai + tr[i];
            mx = fmaxf(mx, term[i]);
        }
        float ssum = 0.f;
        #pragma unroll
        for (int i = 0; i < LL; ++i) ssum += __expf(term[i] - mx);
        float nxt = mx + __logf(ssum) + emj;
        if (act && valid) alpha = nxt;
    }
    float num = score + __shfl(en, prev);
    float av = act ? (alpha + en) : -3e38f;
    float mx = av;
    #pragma unroll
    for (int o = 1; o < 16; o <<= 1) mx = fmaxf(mx, __shfl_xor(mx, o, 16));
    float es = __expf(av - mx);
    #pragma unroll
    for (int o = 1; o < 16; o <<= 1) es += __shfl_xor(es, o, 16);
    float logz = mx + __logf(es);
    if (j == 0) llh[b] = num - logz;
}

__global__ __launch_bounds__(64) void finred(const float* __restrict__ llh, float* __restrict__ out)
{
    float v = llh[threadIdx.x];
    #pragma unroll
    for (int o = 32; o; o >>= 1) v += __shfl_xor(v, o);
    if (threadIdx.x == 0) out[0] = -(v * (1.0f / 64.0f));
}

// ---------------------------------------------------------------------------
extern "C" void kernel_launch(void* const* d_in, const int* in_sizes, int n_in,
                              void* d_out, int out_size, void* d_ws, size_t ws_size,
                              hipStream_t stream) {
    const int*   ids    = (const int*)d_in[0];
    const int*   attn   = (const int*)d_in[1];
    const int*   labels = (const int*)d_in[2];
    const float* emb    = (const float*)d_in[3];
    const float* w_ih_f = (const float*)d_in[4];
    const float* w_hh_f = (const float*)d_in[5];
    const float* b_ih_f = (const float*)d_in[6];
    const float* b_hh_f = (const float*)d_in[7];
    const float* w_ih_b = (const float*)d_in[8];
    const float* w_hh_b = (const float*)d_in[9];
    const float* b_ih_b = (const float*)d_in[10];
    const float* b_hh_b = (const float*)d_in[11];
    const float* w_out  = (const float*)d_in[12];
    const float* b_out  = (const float*)d_in[13];
    const float* start  = (const float*)d_in[14];
    const float* endt   = (const float*)d_in[15];
    const float* trans  = (const float*)d_in[16];

    char* ws = (char*)d_ws;
    unsigned short* xw    = (unsigned short*)(ws);                 // 128 MiB
    unsigned short* h_all = (unsigned short*)(ws + 134217728ull);  // 32 MiB
    unsigned short* h_buf = (unsigned short*)(ws + 167772160ull);  // 256 KiB
    unsigned int*   flags = (unsigned int*)(ws + 168034304ull);    // 2 KiB
    float*          em    = (float*)(ws + 168036352ull);           // 576 KiB
    float*          llh   = (float*)(ws + 168626176ull);           // 256 B

    // zero h(0) double-buffers + flags (ws is poisoned 0xAA before every launch)
    hipMemsetAsync((void*)(ws + 167772160ull), 0, 262144ull + 2048ull, stream);

    xw_gemm<<<dim3(128, 16, 2), 256, 0, stream>>>(ids, emb, w_ih_f, b_ih_f, b_hh_f,
                                                  w_ih_b, b_ih_b, b_hh_b, xw);

    void* rec_args[] = { (void*)&w_hh_f, (void*)&w_hh_b, (void*)&xw,
                         (void*)&h_all, (void*)&h_buf, (void*)&flags };
    hipLaunchCooperativeKernel((const void*)lstm_rec, dim3(128), dim3(256), rec_args, 0, stream);

    emis<<<4096, 256, 0, stream>>>(h_all, w_out, b_out, em);
    crf<<<64, 64, 0, stream>>>(em, labels, attn, start, endt, trans, llh);
    finred<<<1, 64, 0, stream>>>(llh, (float*)d_out);
}

// Round 9
// 975.250 us; speedup vs baseline: 1.6028x; 1.6028x over previous
//
#include <hip/hip_runtime.h>
#include <hip/hip_bf16.h>
#include <hip/hip_cooperative_groups.h>

#define TT 256
#define BB 64
#define HH 512
#define EE 256
#define G4 2048
#define LL 9

typedef short bf16x8 __attribute__((ext_vector_type(8)));
typedef float f32x4 __attribute__((ext_vector_type(4)));
typedef unsigned long long u64;

static __device__ __forceinline__ unsigned short f2bf(float f) {
    unsigned u = __builtin_bit_cast(unsigned, f);
    u += 0x7FFFu + ((u >> 16) & 1u);   // RNE
    return (unsigned short)(u >> 16);
}
static __device__ __forceinline__ float bf2f(unsigned short s) {
    unsigned u = ((unsigned)s) << 16;
    return __builtin_bit_cast(float, u);
}
static __device__ __forceinline__ float sigf(float x) { return 1.f / (1.f + __expf(-x)); }
static __device__ __forceinline__ float tanhf_(float x) {
    float cx = fminf(fmaxf(x, -15.f), 15.f);
    float e = __expf(2.f * cx);
    return (e - 1.f) / (e + 1.f);
}

// ---------------------------------------------------------------------------
// Kernel 1: xW = (emb[ids] @ w_ih^T) + b_ih + b_hh, both directions, bf16 MFMA.
// Output TRANSPOSED: xw[dir][t][n][b] (bf16). (validated)
// ---------------------------------------------------------------------------
__global__ __launch_bounds__(256) void xw_gemm(
    const int* __restrict__ ids, const float* __restrict__ emb,
    const float* __restrict__ w_ih_f, const float* __restrict__ b_ih_f, const float* __restrict__ b_hh_f,
    const float* __restrict__ w_ih_b, const float* __restrict__ b_ih_b, const float* __restrict__ b_hh_b,
    unsigned short* __restrict__ xw)
{
    const int dir = blockIdx.z;
    const float* w_ih = dir ? w_ih_b : w_ih_f;
    const float* bi   = dir ? b_ih_b : b_ih_f;
    const float* bh   = dir ? b_hh_b : b_hh_f;
    const int n0 = blockIdx.y * 128;
    const int m0 = blockIdx.x * 128;
    const int tid = threadIdx.x;
    const int lane = tid & 63;
    const int wave = tid >> 6;
    const int wn = (wave & 1) * 64;
    const int wm = (wave >> 1) * 64;

    __shared__ short Wt[128][40];
    __shared__ short Xt[128][40];

    int rowid[4];
    #pragma unroll
    for (int i = 0; i < 4; ++i) {
        int p = tid + i * 256;
        int r = p >> 3;
        int m = m0 + r;
        int t = m >> 6, b = m & 63;
        int tx = dir ? (TT - 1 - t) : t;
        rowid[i] = ids[b * TT + tx];
    }

    f32x4 acc[4][4];
    #pragma unroll
    for (int a = 0; a < 4; ++a)
        #pragma unroll
        for (int c = 0; c < 4; ++c) acc[a][c] = (f32x4){0.f, 0.f, 0.f, 0.f};

    const int kb8 = (lane >> 4) * 8;
    const int l15 = lane & 15;

    for (int kt = 0; kt < 8; ++kt) {
        int k0 = kt * 32;
        #pragma unroll
        for (int i = 0; i < 4; ++i) {
            int p = tid + i * 256;
            int r = p >> 3;
            int kq = (p & 7) * 4;
            float4 wv = *(const float4*)(w_ih + (size_t)(n0 + r) * EE + k0 + kq);
            *(short4*)&Wt[r][kq] = make_short4((short)f2bf(wv.x), (short)f2bf(wv.y),
                                               (short)f2bf(wv.z), (short)f2bf(wv.w));
            float4 xv = *(const float4*)(emb + (size_t)rowid[i] * EE + k0 + kq);
            *(short4*)&Xt[r][kq] = make_short4((short)f2bf(xv.x), (short)f2bf(xv.y),
                                               (short)f2bf(xv.z), (short)f2bf(xv.w));
        }
        __syncthreads();
        bf16x8 af[4], bfv[4];
        #pragma unroll
        for (int nt = 0; nt < 4; ++nt) af[nt]  = *(const bf16x8*)&Wt[wn + nt * 16 + l15][kb8];
        #pragma unroll
        for (int mt = 0; mt < 4; ++mt) bfv[mt] = *(const bf16x8*)&Xt[wm + mt * 16 + l15][kb8];
        #pragma unroll
        for (int nt = 0; nt < 4; ++nt)
            #pragma unroll
            for (int mt = 0; mt < 4; ++mt)
                acc[nt][mt] = __builtin_amdgcn_mfma_f32_16x16x32_bf16(af[nt], bfv[mt], acc[nt][mt], 0, 0, 0);
        __syncthreads();
    }

    unsigned short* xwp = xw + (size_t)dir * TT * G4 * BB;
    #pragma unroll
    for (int nt = 0; nt < 4; ++nt) {
        #pragma unroll
        for (int r = 0; r < 4; ++r) {
            int n = n0 + wn + nt * 16 + (lane >> 4) * 4 + r;
            float bias = bi[n] + bh[n];
            #pragma unroll
            for (int mt = 0; mt < 4; ++mt) {
                int m = m0 + wm + mt * 16 + l15;
                int t = m >> 6, b = m & 63;
                xwp[((size_t)t * G4 + n) * BB + b] = f2bf(acc[nt][mt][r] + bias);
            }
        }
    }
}

// ---------------------------------------------------------------------------
// Kernel 2: LSTM recurrence — SEQNO-IN-DATA exchange (no flags, no fences).
// Each h granule = 8B atomic store: [data: 2 units bf16 | seq: step+1].
// Consumers poll their own granules until seq == s -> the poll IS the data
// load (one L3 RTT on the critical path). No producer vmcnt drain, no
// release/arrival barriers; one stage-ready s_barrier per step.
// Ring of 2 slices per island. WAR proof: a producer at step s observed all
// of h(s), so every wave finished its slice-(s-1) poll (loads return in
// order); the slot it overwrites, (s+1)&1, is that dead slice.
// LDS: row-major + byte-XOR (row&7)<<4 — stage writes (4B, bank=t^const)
// conflict-free; b128 frag reads 2-way (free).
// ---------------------------------------------------------------------------
__global__ __launch_bounds__(256, 1) void lstm_rec(
    const float* __restrict__ w_hh_f, const float* __restrict__ w_hh_b,
    const unsigned short* __restrict__ xw,   // [2][T][2048][64] bf16
    unsigned short* __restrict__ h_all,      // [2][T][64][512] bf16
    u64* __restrict__ h_ring)                // [8 isl][2 slice][16 row][256 up]
{
    const int wg  = blockIdx.x;
    const int d   = wg >> 6;          // direction
    const int bg  = (wg >> 4) & 3;    // batch group (16 rows)
    const int ug  = wg & 15;          // unit group (32 units)
    const int isl = d * 4 + bg;

    const int tid  = threadIdx.x;
    const int lane = tid & 63;
    const int wv   = tid >> 6;
    const int bl   = lane & 15;       // local batch row
    const int jp   = lane >> 4;       // 0..3
    const int kb8  = jp * 8;
    const int uwb  = ug * 32 + wv * 8;    // wave's unit base (8 units)
    const int u_w  = uwb + jp * 2;        // this thread's 2 units
    const int b_abs = bg * 16 + bl;

    const float* w_hh = d ? w_hh_b : w_hh_f;

    // --- load w_hh fragments into registers (once) ---
    bf16x8 Bf[2][16];
    #pragma unroll
    for (int ct = 0; ct < 2; ++ct) {
        int c = ct * 16 + bl;                 // col within wave's 32
        int g = c >> 3, j = c & 7;
        int n = g * HH + uwb + j;
        #pragma unroll
        for (int ks = 0; ks < 16; ++ks) {
            int k = ks * 32 + kb8;
            float4 w0 = *(const float4*)(w_hh + (size_t)n * HH + k);
            float4 w1 = *(const float4*)(w_hh + (size_t)n * HH + k + 4);
            bf16x8 v;
            v[0] = (short)f2bf(w0.x); v[1] = (short)f2bf(w0.y);
            v[2] = (short)f2bf(w0.z); v[3] = (short)f2bf(w0.w);
            v[4] = (short)f2bf(w1.x); v[5] = (short)f2bf(w1.y);
            v[6] = (short)f2bf(w1.z); v[7] = (short)f2bf(w1.w);
            Bf[ct][ks] = v;
        }
    }

    __shared__ char h_lds[16 * 1024];         // [row][1024B], XOR-swizzled
    __shared__ float gx[4][16 * 33 + 16];     // per-wave transpose region
    float* gw = &gx[wv][0];
    u64* ring = h_ring + (size_t)isl * 2 * 4096;

    float creg0 = 0.f, creg1 = 0.f;

    for (int s = 0; s < TT; ++s) {
        // ---- xw loads for this step: independent of h, issue before poll ----
        const unsigned short* xp = xw + ((size_t)(d * TT + s) * G4) * BB;
        unsigned short xr[4][2];
        #pragma unroll
        for (int g = 0; g < 4; ++g) {
            xr[g][0] = xp[(size_t)(g * HH + u_w + 0) * BB + b_abs];
            xr[g][1] = xp[(size_t)(g * HH + u_w + 1) * BB + b_abs];
        }

        // ---- poll OWN granules of slice s&1 until seq==s (poll == load) ----
        const u64* sl = ring + (size_t)(s & 1) * 4096;
        const unsigned sexp = (unsigned)s;
        u64 g16[16];
        int spin = 0;
        while (true) {
            #pragma unroll
            for (int i = 0; i < 16; ++i)
                g16[i] = __hip_atomic_load(sl + i * 256 + tid, __ATOMIC_RELAXED,
                                           __HIP_MEMORY_SCOPE_AGENT);
            bool mine = true;
            #pragma unroll
            for (int i = 0; i < 16; ++i)
                mine = mine && ((unsigned)(g16[i] >> 32) == sexp);
            if (__all(mine)) break;
            if (++spin > (1 << 13)) break;   // bounded valve: stale -> loud fail
        }

        // ---- stage data halves into LDS (conflict-free 4B writes) ----
        #pragma unroll
        for (int i = 0; i < 16; ++i) {
            unsigned off = i * 1024 + ((tid * 4) ^ ((i & 7) << 4));
            *(unsigned*)(h_lds + off) = (unsigned)g16[i];
        }
        asm volatile("s_waitcnt lgkmcnt(0)" ::: "memory");
        __builtin_amdgcn_sched_barrier(0);
        __builtin_amdgcn_s_barrier();            // h_lds ready (only barrier)
        asm volatile("" ::: "memory");

        // ---- frag read (2-way free) + 32 MFMA ----
        f32x4 acc0 = (f32x4){0.f, 0.f, 0.f, 0.f};
        f32x4 acc1 = (f32x4){0.f, 0.f, 0.f, 0.f};
        #pragma unroll
        for (int ks = 0; ks < 16; ++ks) {
            bf16x8 a = *(const bf16x8*)(h_lds + bl * 1024 + ((ks * 64 + jp * 16) ^ ((bl & 7) << 4)));
            acc0 = __builtin_amdgcn_mfma_f32_16x16x32_bf16(a, Bf[0][ks], acc0, 0, 0, 0);
            acc1 = __builtin_amdgcn_mfma_f32_16x16x32_bf16(a, Bf[1][ks], acc1, 0, 0, 0);
        }

        // ---- per-wave LDS transpose (validated layout, unchanged) ----
        #pragma unroll
        for (int r = 0; r < 4; ++r) {
            gw[(jp * 4 + r) * 33 + 0 * 16 + bl] = acc0[r];
            gw[(jp * 4 + r) * 33 + 1 * 16 + bl] = acc1[r];
        }
        asm volatile("s_waitcnt lgkmcnt(0)" ::: "memory");
        __builtin_amdgcn_sched_barrier(0);
        float gvv[4][2];
        #pragma unroll
        for (int g = 0; g < 4; ++g) {
            gvv[g][0] = gw[bl * 33 + g * 8 + jp * 2 + 0];
            gvv[g][1] = gw[bl * 33 + g * 8 + jp * 2 + 1];
        }

        // ---- gates (fp32) for this thread's 2 units ----
        unsigned int hu = 0;
        {
            float gi = gvv[0][0] + bf2f(xr[0][0]);
            float gf = gvv[1][0] + bf2f(xr[1][0]);
            float gg = gvv[2][0] + bf2f(xr[2][0]);
            float go = gvv[3][0] + bf2f(xr[3][0]);
            float cc = sigf(gf) * creg0 + sigf(gi) * tanhf_(gg);
            float hv = sigf(go) * tanhf_(cc);
            creg0 = cc;
            hu = (unsigned int)f2bf(hv);
        }
        {
            float gi = gvv[0][1] + bf2f(xr[0][1]);
            float gf = gvv[1][1] + bf2f(xr[1][1]);
            float gg = gvv[2][1] + bf2f(xr[2][1]);
            float go = gvv[3][1] + bf2f(xr[3][1]);
            float cc = sigf(gf) * creg1 + sigf(gi) * tanhf_(gg);
            float hv = sigf(go) * tanhf_(cc);
            creg1 = cc;
            hu |= ((unsigned int)f2bf(hv)) << 16;
        }

        // ---- publish: one 8B atomic [data|seq=s+1]; NO drain, NO flag ----
        u64* wsl = ring + (size_t)((s + 1) & 1) * 4096;
        u64 pg = (u64)hu | ((u64)(unsigned)(s + 1) << 32);
        __hip_atomic_store(wsl + (size_t)bl * 256 + (uwb >> 1) + jp, pg,
                           __ATOMIC_RELAXED, __HIP_MEMORY_SCOPE_AGENT);
        int tout = d ? (TT - 1 - s) : s;
        *(unsigned int*)(h_all + ((size_t)(d * TT + tout) * BB + b_abs) * HH + u_w) = hu;
    }
}

// ---------------------------------------------------------------------------
// Kernel 3: emissions (unchanged)
// ---------------------------------------------------------------------------
__global__ __launch_bounds__(256) void emis(
    const unsigned short* __restrict__ h_all,
    const float* __restrict__ w_out, const float* __restrict__ b_out,
    float* __restrict__ em)
{
    int p = blockIdx.x * 4 + (threadIdx.x >> 6);
    int lane = threadIdx.x & 63;
    int t = p >> 6, b = p & 63;
    bf16x8 vf = *(const bf16x8*)(h_all + ((size_t)(0 * TT + t) * BB + b) * HH + lane * 8);
    bf16x8 vb = *(const bf16x8*)(h_all + ((size_t)(1 * TT + t) * BB + b) * HH + lane * 8);
    float hf[8], hbk[8];
    #pragma unroll
    for (int i = 0; i < 8; ++i) { hf[i] = bf2f((unsigned short)vf[i]); hbk[i] = bf2f((unsigned short)vb[i]); }
    #pragma unroll
    for (int l = 0; l < LL; ++l) {
        const float* wr = w_out + (size_t)l * (2 * HH);
        float a = 0.f;
        float4 w0 = *(const float4*)(wr + lane * 8);
        float4 w1 = *(const float4*)(wr + lane * 8 + 4);
        float4 w2 = *(const float4*)(wr + HH + lane * 8);
        float4 w3 = *(const float4*)(wr + HH + lane * 8 + 4);
        a += hf[0]*w0.x + hf[1]*w0.y + hf[2]*w0.z + hf[3]*w0.w;
        a += hf[4]*w1.x + hf[5]*w1.y + hf[6]*w1.z + hf[7]*w1.w;
        a += hbk[0]*w2.x + hbk[1]*w2.y + hbk[2]*w2.z + hbk[3]*w2.w;
        a += hbk[4]*w3.x + hbk[5]*w3.y + hbk[6]*w3.z + hbk[7]*w3.w;
        #pragma unroll
        for (int o = 32; o; o >>= 1) a += __shfl_xor(a, o);
        if (lane == l) em[((size_t)t * BB + b) * LL + l] = a + b_out[l];
    }
}

// ---------------------------------------------------------------------------
// Kernel 4: CRF log-likelihood (unchanged)
// ---------------------------------------------------------------------------
__global__ __launch_bounds__(64) void crf(
    const float* __restrict__ em, const int* __restrict__ labels,
    const int* __restrict__ attn, const float* __restrict__ start,
    const float* __restrict__ endt, const float* __restrict__ trans,
    float* __restrict__ llh)
{
    int b = blockIdx.x;
    int j = threadIdx.x;
    bool act = j < LL;
    int jj = act ? j : 0;
    float tr[LL];
    #pragma unroll
    for (int i = 0; i < LL; ++i) tr[i] = act ? trans[i * LL + j] : 0.f;
    float st = act ? start[j] : 0.f;
    float en = act ? endt[j] : 0.f;

    int lab0 = labels[b * TT];
    int tg0 = (lab0 == -100) ? 0 : lab0;
    float em0 = em[((size_t)0 * BB + b) * LL + jj];
    float alpha = act ? (st + em0) : -3e38f;
    float score = __shfl(st + em0, tg0);
    int prev = tg0;

    for (int t = 1; t < TT; ++t) {
        int lab = labels[b * TT + t];
        int am  = attn[b * TT + t];
        int tg  = (lab == -100) ? 0 : lab;
        bool valid = (lab != -100) && (am > 0);
        float emj = em[((size_t)t * BB + b) * LL + jj];
        float trv = trans[prev * LL + jj];
        float s_tr = __shfl(trv, tg);
        float s_em = __shfl(emj, tg);
        if (valid) { score += s_tr + s_em; prev = tg; }
        float term[LL];
        float mx = -3e38f;
        #pragma unroll
        for (int i = 0; i < LL; ++i) {
            float ai = __shfl(alpha, i);
            term[i] = ai + tr[i];
            mx = fmaxf(mx, term[i]);
        }
        float ssum = 0.f;
        #pragma unroll
        for (int i = 0; i < LL; ++i) ssum += __expf(term[i] - mx);
        float nxt = mx + __logf(ssum) + emj;
        if (act && valid) alpha = nxt;
    }
    float num = score + __shfl(en, prev);
    float av = act ? (alpha + en) : -3e38f;
    float mx = av;
    #pragma unroll
    for (int o = 1; o < 16; o <<= 1) mx = fmaxf(mx, __shfl_xor(mx, o, 16));
    float es = __expf(av - mx);
    #pragma unroll
    for (int o = 1; o < 16; o <<= 1) es += __shfl_xor(es, o, 16);
    float logz = mx + __logf(es);
    if (j == 0) llh[b] = num - logz;
}

__global__ __launch_bounds__(64) void finred(const float* __restrict__ llh, float* __restrict__ out)
{
    float v = llh[threadIdx.x];
    #pragma unroll
    for (int o = 32; o; o >>= 1) v += __shfl_xor(v, o);
    if (threadIdx.x == 0) out[0] = -(v * (1.0f / 64.0f));
}

// ---------------------------------------------------------------------------
extern "C" void kernel_launch(void* const* d_in, const int* in_sizes, int n_in,
                              void* d_out, int out_size, void* d_ws, size_t ws_size,
                              hipStream_t stream) {
    const int*   ids    = (const int*)d_in[0];
    const int*   attn   = (const int*)d_in[1];
    const int*   labels = (const int*)d_in[2];
    const float* emb    = (const float*)d_in[3];
    const float* w_ih_f = (const float*)d_in[4];
    const float* w_hh_f = (const float*)d_in[5];
    const float* b_ih_f = (const float*)d_in[6];
    const float* b_hh_f = (const float*)d_in[7];
    const float* w_ih_b = (const float*)d_in[8];
    const float* w_hh_b = (const float*)d_in[9];
    const float* b_ih_b = (const float*)d_in[10];
    const float* b_hh_b = (const float*)d_in[11];
    const float* w_out  = (const float*)d_in[12];
    const float* b_out  = (const float*)d_in[13];
    const float* start  = (const float*)d_in[14];
    const float* endt   = (const float*)d_in[15];
    const float* trans  = (const float*)d_in[16];

    char* ws = (char*)d_ws;
    unsigned short* xw    = (unsigned short*)(ws);                 // 128 MiB
    unsigned short* h_all = (unsigned short*)(ws + 134217728ull);  // 32 MiB
    u64*            h_ring= (u64*)(ws + 167772160ull);             // 512 KiB (dead after lstm_rec)
    float*          em    = (float*)(ws + 167772160ull);           // 576 KiB (aliases h_ring; written after)
    float*          llh   = (float*)(ws + 168361984ull);           // 256 B

    // zero the seqno ring: slice-0 becomes h(0)=0 with seq=0 for every island
    hipMemsetAsync((void*)h_ring, 0, 524288ull, stream);

    xw_gemm<<<dim3(128, 16, 2), 256, 0, stream>>>(ids, emb, w_ih_f, b_ih_f, b_hh_f,
                                                  w_ih_b, b_ih_b, b_hh_b, xw);

    void* rec_args[] = { (void*)&w_hh_f, (void*)&w_hh_b, (void*)&xw,
                         (void*)&h_all, (void*)&h_ring };
    hipLaunchCooperativeKernel((const void*)lstm_rec, dim3(128), dim3(256), rec_args, 0, stream);

    emis<<<4096, 256, 0, stream>>>(h_all, w_out, b_out, em);
    crf<<<64, 64, 0, stream>>>(em, labels, attn, start, endt, trans, llh);
    finred<<<1, 64, 0, stream>>>(llh, (float*)d_out);
}